// Round 10
// baseline (243.195 us; speedup 1.0000x reference)
//
#include <hip/hip_runtime.h>
#include <math.h>

#define N_NODES 256
#define T_DIM   30000
#define KP      30016   // 469 * 64, padded K for bf16 operands
#define H_DIM   512
#define L_DIM   256

typedef __attribute__((ext_vector_type(8))) short short8;
typedef __attribute__((ext_vector_type(4))) float floatx4;

// fp32 -> bf16 (RNE)
__device__ __forceinline__ unsigned short f2b(float f) {
    unsigned u = __float_as_uint(f);
    u += 0x7fffu + ((u >> 16) & 1u);
    return (unsigned short)(u >> 16);
}

__device__ __forceinline__ float4 zero4() {
    float4 z; z.x = z.y = z.z = z.w = 0.f; return z;
}

// ---------------- mega-prepass (one dispatch) --------------------------------
// blocks [0,3752):    Wt[512][30016] bf16 = transpose(W[30000][512]) (LDS tile)
// blocks [3752,7504): xb[256][30016] bf16 = x[256][30000], zero-padded
// blocks [7504,7568): P = I (edge atomics added later, in the reduce dispatch)
// block  7568:        zero u, dem
__global__ __launch_bounds__(256)
void k_prep(const float* __restrict__ W, const float* __restrict__ x,
            unsigned short* __restrict__ Wt, unsigned short* __restrict__ xb,
            float* __restrict__ P, float* __restrict__ dem,
            float* __restrict__ u) {
    __shared__ float tile[64][65];   // +1 pad: conflict-free transposed read
    const int b = blockIdx.x, t = threadIdx.x;
    if (b < 3752) {                  // ---- Wt transpose ----
        const int k0 = (b % 469) << 6;
        const int c0 = (b / 469) << 6;
        const int rr = t >> 4, c4 = (t & 15) << 2;
        #pragma unroll
        for (int i = 0; i < 4; ++i) {
            const int k = k0 + rr + (i << 4);
            float4 v = (k < T_DIM)
                           ? *(const float4*)&W[(size_t)k * H_DIM + c0 + c4]
                           : zero4();
            tile[rr + (i << 4)][c4 + 0] = v.x;
            tile[rr + (i << 4)][c4 + 1] = v.y;
            tile[rr + (i << 4)][c4 + 2] = v.z;
            tile[rr + (i << 4)][c4 + 3] = v.w;
        }
        __syncthreads();
        const int cr = t >> 4, k4 = (t & 15) << 2;
        #pragma unroll
        for (int i = 0; i < 4; ++i) {
            const int c = cr + (i << 4);
            ushort4 o;
            o.x = f2b(tile[k4 + 0][c]);
            o.y = f2b(tile[k4 + 1][c]);
            o.z = f2b(tile[k4 + 2][c]);
            o.w = f2b(tile[k4 + 3][c]);
            *(ushort4*)&Wt[(size_t)(c0 + c) * KP + k0 + k4] = o;
        }
    } else if (b < 7504) {           // ---- xb convert (8 elems/thread) ----
        const int e0 = (b - 3752) * 2048 + t * 8;   // padded index; 8 | KP
        const int row = e0 / KP;
        const int col = e0 % KP;
        short8 o;
        if (col < T_DIM) {           // 8 | T_DIM: chunk fully in or out
            float4 v0 = *(const float4*)&x[(size_t)row * T_DIM + col];
            float4 v1 = *(const float4*)&x[(size_t)row * T_DIM + col + 4];
            o[0] = (short)f2b(v0.x); o[1] = (short)f2b(v0.y);
            o[2] = (short)f2b(v0.z); o[3] = (short)f2b(v0.w);
            o[4] = (short)f2b(v1.x); o[5] = (short)f2b(v1.y);
            o[6] = (short)f2b(v1.z); o[7] = (short)f2b(v1.w);
        } else {
            o = (short8){0, 0, 0, 0, 0, 0, 0, 0};
        }
        *(short8*)&xb[e0] = o;
    } else if (b < 7568) {           // ---- P = I ----
        const int i0 = ((b - 7504) << 10) + (t << 2);
        float4 v;
        v.x = ((i0 + 0) >> 8) == ((i0 + 0) & 255) ? 1.f : 0.f;
        v.y = ((i0 + 1) >> 8) == ((i0 + 1) & 255) ? 1.f : 0.f;
        v.z = ((i0 + 2) >> 8) == ((i0 + 2) & 255) ? 1.f : 0.f;
        v.w = ((i0 + 3) >> 8) == ((i0 + 3) & 255) ? 1.f : 0.f;
        *(float4*)&P[i0] = v;
    } else {                         // ---- zero u, dem ----
        if (t < 256) u[t] = 0.f;
        if (t == 0) *dem = 0.f;
    }
}

// fallback-only helpers
__global__ void k_init_P(float* P, float* dem, float* u) {
    int t = blockIdx.x * blockDim.x + threadIdx.x;
    P[t] = ((t >> 8) == (t & 255)) ? 1.0f : 0.0f;
    if (t == 0) *dem = 0.0f;
    if (t < 256) u[t] = 0.0f;
}

__global__ void k_count_edges(const int* __restrict__ idx, int E, float* P) {
    int e = blockIdx.x * blockDim.x + threadIdx.x;
    if (e < E) {
        int s = idx[e];
        int d = idx[E + e];
        atomicAdd(&P[d * N_NODES + s], 1.0f);
    }
}

__global__ void k_zero(float* p, int n) {
    int t = blockIdx.x * blockDim.x + threadIdx.x;
    if (t < n) p[t] = 0.0f;
}

// ---------------- merged: split-K reduce + edge atomics (one dispatch) -------
// blocks [0,128):  Y1 = sum_z Y1p[z]  (float4, 32768 items)
// blocks [128,..): one thread per edge, global atomicAdd into P (P=I done in
//                  k_prep; stream order guarantees it precedes this dispatch)
__global__ __launch_bounds__(256)
void k_reduce(const float4* __restrict__ Y1p, float4* __restrict__ Y1, int nz,
              const int* __restrict__ idx, int E, float* __restrict__ P) {
    const int b = blockIdx.x, t = threadIdx.x;
    if (b < 128) {
        const int i = (b << 8) | t;          // 0..32767
        float4 s = Y1p[i];
        #pragma unroll 4
        for (int z = 1; z < nz; ++z) {
            float4 v = Y1p[(size_t)z * 32768 + i];
            s.x += v.x; s.y += v.y; s.z += v.z; s.w += v.w;
        }
        Y1[i] = s;
    } else {
        const int e = ((b - 128) << 8) + t;
        if (e < E) {
            int s = idx[e];
            int d = idx[E + e];
            atomicAdd(&P[d * N_NODES + s], 1.0f);
        }
    }
}

// ---------------- MFMA big GEMM: Y1p[z] = x @ W (K-slice z), zero-LDS --------
// A = xb [256][30016] bf16 rm, B = Wt [512][30016] bf16 rm — both are ALREADY
// in per-lane fragment layout (row/col major along K), so each lane loads its
// MFMA fragments DIRECTLY from global: short8 at (row|col)*KP + k + lq.
// No LDS, no barriers — removes the LDS-pipe bottleneck (24 b128 ops/chunk ≈
// 288 cy vs 154 cy MFMA) and the per-chunk vmcnt(0) barrier drains.
// 128x128 tile, 4 waves (2x2), 4x4 fragments/wave; one 32-k window software
// pipeline (even/odd named sets). 1D grid = 8*nz, XCD-chunked swizzle.
__global__ __launch_bounds__(256)
void k_gemm_bf16(const unsigned short* __restrict__ xb,
                 const unsigned short* __restrict__ Wt,
                 float* __restrict__ outp, int kc) {
    const int t = threadIdx.x;
    const int orig = blockIdx.x;
    const int q = gridDim.x >> 3;             // = nz (gridDim.x = 8*nz)
    const int L = (orig & 7) * q + (orig >> 3);
    const int tile = L & 7;
    const int colBase = (tile & 3) << 7;
    const int rowBase = (tile >> 2) << 7;
    const int z = L >> 3;
    const int kb0 = z * kc;                   // elements, multiple of 64
    const int kend = min(kb0 + kc, KP);
    const int nchunk = (kend - kb0) >> 6;

    // wave / fragment indexing
    const int w    = t >> 6;
    const int wr   = (w >> 1) << 6;
    const int wc   = (w & 1) << 6;
    const int lane = t & 63;
    const int lm   = lane & 15;
    const int lq   = (lane >> 4) << 3;  // k offset within 32-window: 0,8,16,24

    // per-lane fragment base pointers (fragment i at +i*16*KP)
    const unsigned short* ap0 = xb + (size_t)(rowBase + wr + lm) * KP + lq;
    const unsigned short* bp0 = Wt + (size_t)(colBase + wc + lm) * KP + lq;

    floatx4 acc[4][4];
    #pragma unroll
    for (int i = 0; i < 4; ++i)
        #pragma unroll
        for (int j = 0; j < 4; ++j)
            acc[i][j] = (floatx4){0.f, 0.f, 0.f, 0.f};

    short8 aE[4], bE[4], aO[4], bO[4];

#define LDF(SA, SB, KO) do {                                                   \
        _Pragma("unroll")                                                      \
        for (int i_ = 0; i_ < 4; ++i_)                                         \
            SA[i_] = *(const short8*)(ap0 + (size_t)(i_ * 16) * KP + (KO));    \
        _Pragma("unroll")                                                      \
        for (int j_ = 0; j_ < 4; ++j_)                                         \
            SB[j_] = *(const short8*)(bp0 + (size_t)(j_ * 16) * KP + (KO));    \
    } while (0)

    LDF(aE, bE, kb0);                      // prologue: first even window

    #pragma unroll 1
    for (int c = 0; c < nchunk; ++c) {
        const int kb = kb0 + c * 64;
        LDF(aO, bO, kb + 32);              // issue odd-window loads
        #pragma unroll
        for (int i = 0; i < 4; ++i)
            #pragma unroll
            for (int j = 0; j < 4; ++j)
                acc[i][j] = __builtin_amdgcn_mfma_f32_16x16x32_bf16(
                    aE[i], bE[j], acc[i][j], 0, 0, 0);
        if (c + 1 < nchunk) LDF(aE, bE, kb + 64);   // issue next even window
        #pragma unroll
        for (int i = 0; i < 4; ++i)
            #pragma unroll
            for (int j = 0; j < 4; ++j)
                acc[i][j] = __builtin_amdgcn_mfma_f32_16x16x32_bf16(
                    aO[i], bO[j], acc[i][j], 0, 0, 0);
    }
#undef LDF

    // epilogue: D rows = quad*4+reg, col = lane&15 (m89-verified layout)
    float* op = outp + (size_t)z * (N_NODES * H_DIM);
    const int rq = (lane >> 4) << 2;
    #pragma unroll
    for (int i = 0; i < 4; ++i) {
        #pragma unroll
        for (int j = 0; j < 4; ++j) {
            const int r  = rowBase + wr + i * 16 + rq;
            const int cc = colBase + wc + j * 16 + lm;
            op[(size_t)(r + 0) * H_DIM + cc] = acc[i][j][0];
            op[(size_t)(r + 1) * H_DIM + cc] = acc[i][j][1];
            op[(size_t)(r + 2) * H_DIM + cc] = acc[i][j][2];
            op[(size_t)(r + 3) * H_DIM + cc] = acc[i][j][3];
        }
    }
}

// fallback fp32 GEMM (atomic) if workspace too small for Wt/xb + partials
__global__ __launch_bounds__(256)
void k_gemm_big_atomic(const float* __restrict__ x, const float* __restrict__ W,
                       float* __restrict__ outp, int kc) {
    __shared__ float xs[16 * 140];
    __shared__ float ws[16 * 132];
    const int t  = threadIdx.x;
    const int colBase = blockIdx.x * 128;
    const int rowBase = blockIdx.y * 128;
    const int kb0  = blockIdx.z * kc;
    const int kend = min(kb0 + kc, T_DIM);
    const int nchunk = (kend > kb0) ? ((kend - kb0) >> 4) : 0;
    const int lr  = t >> 2, lkq = (t & 3) * 4;
    const int wkk = t >> 5, wcq = (t & 31) * 4;
    const int tx  = t & 15, ty = t >> 4;
    float acc[8][8];
    #pragma unroll
    for (int i = 0; i < 8; ++i)
        #pragma unroll
        for (int j = 0; j < 8; ++j) acc[i][j] = 0.0f;
    #pragma unroll 1
    for (int c = 0; c < nchunk; ++c) {
        int kb = kb0 + c * 16;
        __syncthreads();
        const float* xp = x + (size_t)(rowBase + lr) * T_DIM + kb + lkq;
        float4 xa = *(const float4*)xp;
        float4 xb4 = *(const float4*)(xp + (size_t)64 * T_DIM);
        const float* wp = W + (size_t)(kb + wkk) * H_DIM + colBase + wcq;
        float4 wa = *(const float4*)wp;
        float4 wb = *(const float4*)(wp + 8 * H_DIM);
        xs[(lkq + 0) * 140 + lr] = xa.x; xs[(lkq + 1) * 140 + lr] = xa.y;
        xs[(lkq + 2) * 140 + lr] = xa.z; xs[(lkq + 3) * 140 + lr] = xa.w;
        xs[(lkq + 0) * 140 + lr + 64] = xb4.x; xs[(lkq + 1) * 140 + lr + 64] = xb4.y;
        xs[(lkq + 2) * 140 + lr + 64] = xb4.z; xs[(lkq + 3) * 140 + lr + 64] = xb4.w;
        *(float4*)&ws[wkk * 132 + wcq]       = wa;
        *(float4*)&ws[(wkk + 8) * 132 + wcq] = wb;
        __syncthreads();
        #pragma unroll
        for (int kk = 0; kk < 16; ++kk) {
            float a[8], b[8];
            *(float4*)&a[0] = *(const float4*)&xs[kk * 140 + ty * 8];
            *(float4*)&a[4] = *(const float4*)&xs[kk * 140 + ty * 8 + 4];
            *(float4*)&b[0] = *(const float4*)&ws[kk * 132 + tx * 8];
            *(float4*)&b[4] = *(const float4*)&ws[kk * 132 + tx * 8 + 4];
            #pragma unroll
            for (int i = 0; i < 8; ++i)
                #pragma unroll
                for (int j = 0; j < 8; ++j)
                    acc[i][j] = fmaf(a[i], b[j], acc[i][j]);
        }
    }
    if (nchunk == 0) return;
    #pragma unroll
    for (int i = 0; i < 8; ++i) {
        int r = rowBase + ty * 8 + i;
        #pragma unroll
        for (int j = 0; j < 8; ++j)
            atomicAdd(&outp[r * H_DIM + colBase + tx * 8 + j], acc[i][j]);
    }
}

// ---------------- MFMA stage GEMM: one 16x16 tile per 1-wave block -----------
// out[256 x N] = act(A[256 x K] @ B[K x N] + bias); operands fp32 from global
// (L2-resident), converted fp32->bf16 in-register. Grid = 16*(N/16) blocks of
// 64 threads (1 wave) -> spreads across all 256 CUs.
// MODE 0: store; MODE 1: store + dementia dot; MODE 2: u-fuse only, no store.
template<int K, int N, int MODE>
__global__ __launch_bounds__(64)
void k_mstage(const float* __restrict__ A, const float* __restrict__ B,
              const float* __restrict__ bias, float* __restrict__ out, int act,
              const float* __restrict__ Wd, float* __restrict__ dem,
              const float* __restrict__ uW, float* __restrict__ u) {
    const int lane = threadIdx.x;
    const int wv = blockIdx.x;
    const int nct = N >> 4;
    const int r0 = (wv / nct) << 4;
    const int c0 = (wv % nct) << 4;
    const int lm   = lane & 15;
    const int lq   = (lane >> 4) << 3;   // k slice offset 0,8,16,24

    floatx4 accE = {0.f, 0.f, 0.f, 0.f};
    floatx4 accO = {0.f, 0.f, 0.f, 0.f};
    const float* ap = A + (size_t)(r0 + lm) * K + lq;
    const float* bp = B + (size_t)lq * N + c0 + lm;

    #pragma unroll 2
    for (int kb = 0; kb < K; kb += 64) {
        {   // k-step kb (even accumulator)
            float4 a0 = *(const float4*)(ap + kb);
            float4 a1 = *(const float4*)(ap + kb + 4);
            const float* bq = bp + (size_t)kb * N;
            float b0 = bq[0],           b1 = bq[(size_t)N];
            float b2 = bq[(size_t)2*N], b3 = bq[(size_t)3*N];
            float b4 = bq[(size_t)4*N], b5 = bq[(size_t)5*N];
            float b6 = bq[(size_t)6*N], b7 = bq[(size_t)7*N];
            short8 af, bf;
            af[0] = (short)f2b(a0.x); af[1] = (short)f2b(a0.y);
            af[2] = (short)f2b(a0.z); af[3] = (short)f2b(a0.w);
            af[4] = (short)f2b(a1.x); af[5] = (short)f2b(a1.y);
            af[6] = (short)f2b(a1.z); af[7] = (short)f2b(a1.w);
            bf[0] = (short)f2b(b0); bf[1] = (short)f2b(b1);
            bf[2] = (short)f2b(b2); bf[3] = (short)f2b(b3);
            bf[4] = (short)f2b(b4); bf[5] = (short)f2b(b5);
            bf[6] = (short)f2b(b6); bf[7] = (short)f2b(b7);
            accE = __builtin_amdgcn_mfma_f32_16x16x32_bf16(af, bf, accE, 0, 0, 0);
        }
        {   // k-step kb+32 (odd accumulator)
            const int k2 = kb + 32;
            float4 a0 = *(const float4*)(ap + k2);
            float4 a1 = *(const float4*)(ap + k2 + 4);
            const float* bq = bp + (size_t)k2 * N;
            float b0 = bq[0],           b1 = bq[(size_t)N];
            float b2 = bq[(size_t)2*N], b3 = bq[(size_t)3*N];
            float b4 = bq[(size_t)4*N], b5 = bq[(size_t)5*N];
            float b6 = bq[(size_t)6*N], b7 = bq[(size_t)7*N];
            short8 af, bf;
            af[0] = (short)f2b(a0.x); af[1] = (short)f2b(a0.y);
            af[2] = (short)f2b(a0.z); af[3] = (short)f2b(a0.w);
            af[4] = (short)f2b(a1.x); af[5] = (short)f2b(a1.y);
            af[6] = (short)f2b(a1.z); af[7] = (short)f2b(a1.w);
            bf[0] = (short)f2b(b0); bf[1] = (short)f2b(b1);
            bf[2] = (short)f2b(b2); bf[3] = (short)f2b(b3);
            bf[4] = (short)f2b(b4); bf[5] = (short)f2b(b5);
            bf[6] = (short)f2b(b6); bf[7] = (short)f2b(b7);
            accO = __builtin_amdgcn_mfma_f32_16x16x32_bf16(af, bf, accO, 0, 0, 0);
        }
    }

    const float bb = bias ? bias[c0 + lm] : 0.f;
    const int rq = (lane >> 4) << 2;
    float v[4];
    #pragma unroll
    for (int i = 0; i < 4; ++i) {
        v[i] = accE[i] + accO[i] + bb;
        if (act) v[i] = fmaxf(v[i], 0.f);
    }

    if (MODE == 2) {
        const float uw = uW[c0 + lm];
        #pragma unroll
        for (int i = 0; i < 4; ++i) {
            float p = v[i] * uw;
            #pragma unroll
            for (int off = 8; off; off >>= 1) p += __shfl_down(p, off, 16);
            if (lm == 0) atomicAdd(&u[r0 + rq + i], p);
        }
        return;
    }
    #pragma unroll
    for (int i = 0; i < 4; ++i)
        out[(size_t)(r0 + rq + i) * N + c0 + lm] = v[i];
    if (MODE == 1) {
        float p = 0.f;
        #pragma unroll
        for (int i = 0; i < 4; ++i)
            p += v[i] * Wd[(r0 + rq + i) * 256 + c0 + lm];
        #pragma unroll
        for (int off = 32; off; off >>= 1) p += __shfl_down(p, off, 64);
        if (lane == 0) atomicAdd(dem, p);
    }
}

__device__ __forceinline__ float sigmoidf(float x) {
    return 1.0f / (1.0f + expf(-x));
}

// final: v = P@u per row -> region scores; block 0 emits dementia pred
__global__ __launch_bounds__(256)
void k_final(const float* __restrict__ P, const float* __restrict__ u,
             const float* __restrict__ dem,
             const float* __restrict__ bc2a, const float* __restrict__ Wc2b,
             const float* __restrict__ bc2b, const float* __restrict__ bd,
             float* __restrict__ out) {
    __shared__ float red[4];
    const int b = blockIdx.x, t = threadIdx.x;
    float pv = P[b * 256 + t] * u[t];
    #pragma unroll
    for (int off = 32; off; off >>= 1) pv += __shfl_down(pv, off, 64);
    if ((t & 63) == 0) red[t >> 6] = pv;
    __syncthreads();
    if (t == 0) {
        float v = red[0] + red[1] + red[2] + red[3];
        float h2 = fmaxf(v + bc2a[0], 0.f);
        out[1 + b] = sigmoidf(h2 * Wc2b[0] + bc2b[0]);
        if (b == 0) out[0] = sigmoidf(*dem + bd[0]);
    }
}

extern "C" void kernel_launch(void* const* d_in, const int* in_sizes, int n_in,
                              void* d_out, int out_size, void* d_ws, size_t ws_size,
                              hipStream_t stream) {
    const float* x    = (const float*)d_in[0];
    const int*   idx  = (const int*)d_in[1];
    const float* Ws1a = (const float*)d_in[3];
    const float* bs1a = (const float*)d_in[4];
    const float* Ws1b = (const float*)d_in[5];
    const float* bs1b = (const float*)d_in[6];
    const float* Ws2a = (const float*)d_in[7];
    const float* bs2a = (const float*)d_in[8];
    const float* Ws2b = (const float*)d_in[9];
    const float* bs2b = (const float*)d_in[10];
    const float* Wc1a = (const float*)d_in[11];
    const float* bc1a = (const float*)d_in[12];
    const float* Wc1b = (const float*)d_in[13];
    const float* bc1b = (const float*)d_in[14];
    const float* Wc2a = (const float*)d_in[15];
    const float* bc2a = (const float*)d_in[16];
    const float* Wc2b = (const float*)d_in[17];
    const float* bc2b = (const float*)d_in[18];
    const float* Wd   = (const float*)d_in[19];
    const float* bd   = (const float*)d_in[20];
    float* out = (float*)d_out;
    const int E = in_sizes[1] / 2;

    float* w    = (float*)d_ws;
    float* P    = w;                  // 65536
    float* Y1   = P + 65536;          // 131072
    float* bufA = Y1 + 131072;        // 131072
    float* bufB = bufA + 131072;      // 131072
    float* feat = bufB + 131072;      // 65536
    float* u    = feat + 65536;       // 256
    float* dem  = u + 256;            // 64 (dem + pad)
    float* WtF  = dem + 64;           // Wt bf16: 512*30016*2B
    const size_t WT_F = ((size_t)H_DIM * KP) / 2;     // 7,684,096 f32 slots
    float* XbF  = WtF + WT_F;         // xb bf16: 256*30016*2B
    const size_t XB_F = ((size_t)N_NODES * KP) / 2;   // 3,842,048 f32 slots
    float* Y1p  = XbF + XB_F;
    unsigned short* Wt = (unsigned short*)WtF;
    unsigned short* xb = (unsigned short*)XbF;

    // split-K slicing: 469 chunks of BK=64 (KP=30016)
    const long long fixed = (long long)(Y1p - w);
    const long long avail = (long long)(ws_size / 4) - fixed;
    int maxsplit = (avail > 0) ? (int)(avail / 131072) : 0;
    int nz = 0, kc = 0;
    const int CH64 = 469;
    if (maxsplit >= 2) {
        int splits = maxsplit < 64 ? maxsplit : 64;  // cps=8 -> nz=59, 472 blocks
        int cps = (CH64 + splits - 1) / splits;
        nz = (CH64 + cps - 1) / cps;
        kc = cps * 64;                // elements per z-slice
    }

    if (nz > 0) {
        // prepass: Wt, xb, P=I, zero u/dem (one dispatch)
        k_prep<<<7569, 256, 0, stream>>>(Ws1a, x, Wt, xb, P, dem, u);
        // Y1 = x @ Ws1a   (P@(x@W) == (P@x)@W)  — zero-LDS direct-fragment gemm
        k_gemm_bf16<<<8 * nz, 256, 0, stream>>>(xb, Wt, Y1p, kc);
        // split-K reduce + edge atomics into P (one dispatch)
        k_reduce<<<128 + (E + 255) / 256, 256, 0, stream>>>(
            (const float4*)Y1p, (float4*)Y1, nz, idx, E, P);
    } else {
        k_init_P<<<256, 256, 0, stream>>>(P, dem, u);
        k_count_edges<<<(E + 255) / 256, 256, 0, stream>>>(idx, E, P);
        k_zero<<<512, 256, 0, stream>>>(Y1, N_NODES * H_DIM);
        k_gemm_big_atomic<<<dim3(4, 2, 63), 256, 0, stream>>>(x, Ws1a, Y1, 480);
    }

    // stage chain (stream order is the barrier); 16x16 tile per 1-wave block
    k_mstage<256, 512, 0><<<512, 64, 0, stream>>>(P,    Y1,   bs1a, bufA, 1, 0, 0, 0, 0);
    k_mstage<512, 512, 0><<<512, 64, 0, stream>>>(bufA, Ws1b, bs1b, bufB, 1, 0, 0, 0, 0);
    k_mstage<256, 512, 0><<<512, 64, 0, stream>>>(P,    bufB, 0,    bufA, 0, 0, 0, 0, 0);
    k_mstage<512, 256, 0><<<256, 64, 0, stream>>>(bufA, Ws2a, bs2a, bufB, 1, 0, 0, 0, 0);
    k_mstage<256, 256, 1><<<256, 64, 0, stream>>>(bufB, Ws2b, bs2b, feat, 0, Wd, dem, 0, 0);
    k_mstage<256, 256, 0><<<256, 64, 0, stream>>>(P,    feat, 0,    bufA, 0, 0, 0, 0, 0);
    k_mstage<256, 512, 0><<<512, 64, 0, stream>>>(bufA, Wc1a, bc1a, bufB, 1, 0, 0, 0, 0);
    k_mstage<512, 512, 2><<<512, 64, 0, stream>>>(bufB, Wc1b, bc1b, 0,    1, 0, 0, Wc2a, u);
    k_final<<<256, 256, 0, stream>>>(P, u, dem, bc2a, Wc2b, bc2b, bd, out);
}

// Round 12
// 226.996 us; speedup vs baseline: 1.0714x; 1.0714x over previous
//
#include <hip/hip_runtime.h>
#include <math.h>

#define N_NODES 256
#define T_DIM   30000
#define KP      30016   // 469 * 64, padded K for bf16 operands
#define H_DIM   512
#define L_DIM   256

typedef __attribute__((ext_vector_type(8))) short short8;
typedef __attribute__((ext_vector_type(4))) float floatx4;

// fp32 -> bf16 (RNE)
__device__ __forceinline__ unsigned short f2b(float f) {
    unsigned u = __float_as_uint(f);
    u += 0x7fffu + ((u >> 16) & 1u);
    return (unsigned short)(u >> 16);
}

__device__ __forceinline__ float4 zero4() {
    float4 z; z.x = z.y = z.z = z.w = 0.f; return z;
}

// ---------------- mega-prepass (one dispatch) --------------------------------
// blocks [0,3752):    Wt[512][30016] bf16 = transpose(W[30000][512]) (LDS tile)
// blocks [3752,7504): xb[256][30016] bf16 = x[256][30000], zero-padded
// blocks [7504,7568): P = I (edge atomics added later, in the reduce dispatch)
// block  7568:        zero u, dem
__global__ __launch_bounds__(256)
void k_prep(const float* __restrict__ W, const float* __restrict__ x,
            unsigned short* __restrict__ Wt, unsigned short* __restrict__ xb,
            float* __restrict__ P, float* __restrict__ dem,
            float* __restrict__ u) {
    __shared__ float tile[64][65];   // +1 pad: conflict-free transposed read
    const int b = blockIdx.x, t = threadIdx.x;
    if (b < 3752) {                  // ---- Wt transpose ----
        const int k0 = (b % 469) << 6;
        const int c0 = (b / 469) << 6;
        const int rr = t >> 4, c4 = (t & 15) << 2;
        #pragma unroll
        for (int i = 0; i < 4; ++i) {
            const int k = k0 + rr + (i << 4);
            float4 v = (k < T_DIM)
                           ? *(const float4*)&W[(size_t)k * H_DIM + c0 + c4]
                           : zero4();
            tile[rr + (i << 4)][c4 + 0] = v.x;
            tile[rr + (i << 4)][c4 + 1] = v.y;
            tile[rr + (i << 4)][c4 + 2] = v.z;
            tile[rr + (i << 4)][c4 + 3] = v.w;
        }
        __syncthreads();
        const int cr = t >> 4, k4 = (t & 15) << 2;
        #pragma unroll
        for (int i = 0; i < 4; ++i) {
            const int c = cr + (i << 4);
            ushort4 o;
            o.x = f2b(tile[k4 + 0][c]);
            o.y = f2b(tile[k4 + 1][c]);
            o.z = f2b(tile[k4 + 2][c]);
            o.w = f2b(tile[k4 + 3][c]);
            *(ushort4*)&Wt[(size_t)(c0 + c) * KP + k0 + k4] = o;
        }
    } else if (b < 7504) {           // ---- xb convert (8 elems/thread) ----
        const int e0 = (b - 3752) * 2048 + t * 8;   // padded index; 8 | KP
        const int row = e0 / KP;
        const int col = e0 % KP;
        short8 o;
        if (col < T_DIM) {           // 8 | T_DIM: chunk fully in or out
            float4 v0 = *(const float4*)&x[(size_t)row * T_DIM + col];
            float4 v1 = *(const float4*)&x[(size_t)row * T_DIM + col + 4];
            o[0] = (short)f2b(v0.x); o[1] = (short)f2b(v0.y);
            o[2] = (short)f2b(v0.z); o[3] = (short)f2b(v0.w);
            o[4] = (short)f2b(v1.x); o[5] = (short)f2b(v1.y);
            o[6] = (short)f2b(v1.z); o[7] = (short)f2b(v1.w);
        } else {
            o = (short8){0, 0, 0, 0, 0, 0, 0, 0};
        }
        *(short8*)&xb[e0] = o;
    } else if (b < 7568) {           // ---- P = I ----
        const int i0 = ((b - 7504) << 10) + (t << 2);
        float4 v;
        v.x = ((i0 + 0) >> 8) == ((i0 + 0) & 255) ? 1.f : 0.f;
        v.y = ((i0 + 1) >> 8) == ((i0 + 1) & 255) ? 1.f : 0.f;
        v.z = ((i0 + 2) >> 8) == ((i0 + 2) & 255) ? 1.f : 0.f;
        v.w = ((i0 + 3) >> 8) == ((i0 + 3) & 255) ? 1.f : 0.f;
        *(float4*)&P[i0] = v;
    } else {                         // ---- zero u, dem ----
        if (t < 256) u[t] = 0.f;
        if (t == 0) *dem = 0.f;
    }
}

// fallback-only helpers
__global__ void k_init_P(float* P, float* dem, float* u) {
    int t = blockIdx.x * blockDim.x + threadIdx.x;
    P[t] = ((t >> 8) == (t & 255)) ? 1.0f : 0.0f;
    if (t == 0) *dem = 0.0f;
    if (t < 256) u[t] = 0.0f;
}

__global__ void k_count_edges(const int* __restrict__ idx, int E, float* P) {
    int e = blockIdx.x * blockDim.x + threadIdx.x;
    if (e < E) {
        int s = idx[e];
        int d = idx[E + e];
        atomicAdd(&P[d * N_NODES + s], 1.0f);
    }
}

__global__ void k_zero(float* p, int n) {
    int t = blockIdx.x * blockDim.x + threadIdx.x;
    if (t < n) p[t] = 0.0f;
}

// ---------------- merged: split-K reduce + edge atomics (one dispatch) -------
// blocks [0,128):  Y1 = sum_z Y1p[z]  (float4, 32768 items)
// blocks [128,..): one thread per edge, global atomicAdd into P (P=I done in
//                  k_prep; stream order guarantees it precedes this dispatch)
__global__ __launch_bounds__(256)
void k_reduce(const float4* __restrict__ Y1p, float4* __restrict__ Y1, int nz,
              const int* __restrict__ idx, int E, float* __restrict__ P) {
    const int b = blockIdx.x, t = threadIdx.x;
    if (b < 128) {
        const int i = (b << 8) | t;          // 0..32767
        float4 s = Y1p[i];
        #pragma unroll 4
        for (int z = 1; z < nz; ++z) {
            float4 v = Y1p[(size_t)z * 32768 + i];
            s.x += v.x; s.y += v.y; s.z += v.z; s.w += v.w;
        }
        Y1[i] = s;
    } else {
        const int e = ((b - 128) << 8) + t;
        if (e < E) {
            int s = idx[e];
            int d = idx[E + e];
            atomicAdd(&P[d * N_NODES + s], 1.0f);
        }
    }
}

// ---------------- MFMA big GEMM: Y1p[z] = x @ W (K-slice z), all-bf16 --------
// A = xb [256][30016] bf16 rm, B = Wt [512][30016] bf16 rm (both zero-padded).
// 128x128 tile, BK=64, 1D grid = 8*nz, XCD-chunked swizzle. Staging fully
// coalesced short8; LDS [128][64] bf16 with T2 XOR granule swizzle
// (granule ^= row&7) on write AND read -> conflict-free b128 ds ops.
// NOTE (R10 post-mortem): the zero-LDS direct-fragment variant regressed
// (+14 us) — LDS staging de-duplicates operand traffic (each row/col window
// otherwise fetched 2x per block from L2); keep this staged form.
__global__ __launch_bounds__(256)
void k_gemm_bf16(const unsigned short* __restrict__ xb,
                 const unsigned short* __restrict__ Wt,
                 float* __restrict__ outp, int kc) {
    __shared__ __align__(16) unsigned short Al[128 * 64]; // 16 KB
    __shared__ __align__(16) unsigned short Bl[128 * 64]; // 16 KB

    const int t = threadIdx.x;
    const int orig = blockIdx.x;
    const int q = gridDim.x >> 3;             // = nz (gridDim.x = 8*nz)
    const int L = (orig & 7) * q + (orig >> 3);
    const int tile = L & 7;
    const int colBase = (tile & 3) << 7;
    const int rowBase = (tile >> 2) << 7;
    const int z = L >> 3;
    const int kb0 = z * kc;                   // elements, multiple of 64
    const int kend = min(kb0 + kc, KP);
    const int nchunk = (kend - kb0) >> 6;

    // A staging: row = t>>1 (0..127), granule base = (t&1)*4 (granule=16B)
    const int sr = t >> 1, sg = (t & 1) << 2;
    // B staging: row = t>>3 (+32i), granule = t&7
    const int br = t >> 3, bhc = t & 7;
    const unsigned short* axp = xb + (size_t)(rowBase + sr) * KP + sg * 8;
    const unsigned short* bwp = Wt + (size_t)(colBase + br) * KP + bhc * 8;

    // wave / fragment indexing
    const int w    = t >> 6;
    const int wr   = (w >> 1) << 6;
    const int wc   = (w & 1) << 6;
    const int lane = t & 63;
    const int lm   = lane & 15;
    const int lq   = (lane >> 4) << 3;  // k offset within 32-step: 0,8,16,24

    floatx4 acc[4][4];
    #pragma unroll
    for (int i = 0; i < 4; ++i)
        #pragma unroll
        for (int j = 0; j < 4; ++j)
            acc[i][j] = (floatx4){0.f, 0.f, 0.f, 0.f};

    short8 pa[4], pb[4];

#define GLOAD(C) do {                                                          \
        const int kg_ = kb0 + (C) * 64;                                        \
        _Pragma("unroll")                                                      \
        for (int i_ = 0; i_ < 4; ++i_)                                         \
            pa[i_] = *(const short8*)(axp + kg_ + i_ * 8);                     \
        _Pragma("unroll")                                                      \
        for (int i_ = 0; i_ < 4; ++i_)                                         \
            pb[i_] = *(const short8*)(bwp + (size_t)(32 * i_) * KP + kg_);     \
    } while (0)

    GLOAD(0);

    #pragma unroll 1
    for (int c = 0; c < nchunk; ++c) {
        __syncthreads();
        // A: swizzled ds_write_b128 (granule ^= row&7)
        #pragma unroll
        for (int i = 0; i < 4; ++i) {
            const int ga = (sg + i) ^ (sr & 7);
            *(short8*)&Al[sr * 64 + ga * 8] = pa[i];
        }
        // B: swizzled ds_write_b128
        #pragma unroll
        for (int i = 0; i < 4; ++i) {
            const int row = br + 32 * i;
            const int gb  = bhc ^ (row & 7);
            *(short8*)&Bl[row * 64 + gb * 8] = pb[i];
        }
        __syncthreads();

        if (c + 1 < nchunk) GLOAD(c + 1);   // reg prefetch next chunk

        #pragma unroll
        for (int s = 0; s < 2; ++s) {       // two 32-k MFMA steps per chunk
            const int gbase = (s << 2) | (lq >> 3);
            short8 af[4], bf[4];
            #pragma unroll
            for (int i = 0; i < 4; ++i) {
                const int R = wr + i * 16 + lm;
                af[i] = *(const short8*)&Al[R * 64 + ((gbase ^ (R & 7)) << 3)];
            }
            #pragma unroll
            for (int j = 0; j < 4; ++j) {
                const int Cc = wc + j * 16 + lm;
                bf[j] = *(const short8*)&Bl[Cc * 64 + ((gbase ^ (Cc & 7)) << 3)];
            }
            #pragma unroll
            for (int i = 0; i < 4; ++i)
                #pragma unroll
                for (int j = 0; j < 4; ++j)
                    acc[i][j] = __builtin_amdgcn_mfma_f32_16x16x32_bf16(
                        af[i], bf[j], acc[i][j], 0, 0, 0);
        }
    }
#undef GLOAD

    // epilogue: D rows = quad*4+reg, col = lane&15 (m89-verified layout)
    float* op = outp + (size_t)z * (N_NODES * H_DIM);
    const int rq = (lane >> 4) << 2;
    #pragma unroll
    for (int i = 0; i < 4; ++i) {
        #pragma unroll
        for (int j = 0; j < 4; ++j) {
            const int r  = rowBase + wr + i * 16 + rq;
            const int cc = colBase + wc + j * 16 + lm;
            op[(size_t)(r + 0) * H_DIM + cc] = acc[i][j][0];
            op[(size_t)(r + 1) * H_DIM + cc] = acc[i][j][1];
            op[(size_t)(r + 2) * H_DIM + cc] = acc[i][j][2];
            op[(size_t)(r + 3) * H_DIM + cc] = acc[i][j][3];
        }
    }
}

// fallback fp32 GEMM (atomic) if workspace too small for Wt/xb + partials
__global__ __launch_bounds__(256)
void k_gemm_big_atomic(const float* __restrict__ x, const float* __restrict__ W,
                       float* __restrict__ outp, int kc) {
    __shared__ float xs[16 * 140];
    __shared__ float ws[16 * 132];
    const int t  = threadIdx.x;
    const int colBase = blockIdx.x * 128;
    const int rowBase = blockIdx.y * 128;
    const int kb0  = blockIdx.z * kc;
    const int kend = min(kb0 + kc, T_DIM);
    const int nchunk = (kend > kb0) ? ((kend - kb0) >> 4) : 0;
    const int lr  = t >> 2, lkq = (t & 3) * 4;
    const int wkk = t >> 5, wcq = (t & 31) * 4;
    const int tx  = t & 15, ty = t >> 4;
    float acc[8][8];
    #pragma unroll
    for (int i = 0; i < 8; ++i)
        #pragma unroll
        for (int j = 0; j < 8; ++j) acc[i][j] = 0.0f;
    #pragma unroll 1
    for (int c = 0; c < nchunk; ++c) {
        int kb = kb0 + c * 16;
        __syncthreads();
        const float* xp = x + (size_t)(rowBase + lr) * T_DIM + kb + lkq;
        float4 xa = *(const float4*)xp;
        float4 xb4 = *(const float4*)(xp + (size_t)64 * T_DIM);
        const float* wp = W + (size_t)(kb + wkk) * H_DIM + colBase + wcq;
        float4 wa = *(const float4*)wp;
        float4 wb = *(const float4*)(wp + 8 * H_DIM);
        xs[(lkq + 0) * 140 + lr] = xa.x; xs[(lkq + 1) * 140 + lr] = xa.y;
        xs[(lkq + 2) * 140 + lr] = xa.z; xs[(lkq + 3) * 140 + lr] = xa.w;
        xs[(lkq + 0) * 140 + lr + 64] = xb4.x; xs[(lkq + 1) * 140 + lr + 64] = xb4.y;
        xs[(lkq + 2) * 140 + lr + 64] = xb4.z; xs[(lkq + 3) * 140 + lr + 64] = xb4.w;
        *(float4*)&ws[wkk * 132 + wcq]       = wa;
        *(float4*)&ws[(wkk + 8) * 132 + wcq] = wb;
        __syncthreads();
        #pragma unroll
        for (int kk = 0; kk < 16; ++kk) {
            float a[8], b[8];
            *(float4*)&a[0] = *(const float4*)&xs[kk * 140 + ty * 8];
            *(float4*)&a[4] = *(const float4*)&xs[kk * 140 + ty * 8 + 4];
            *(float4*)&b[0] = *(const float4*)&ws[kk * 132 + tx * 8];
            *(float4*)&b[4] = *(const float4*)&ws[kk * 132 + tx * 8 + 4];
            #pragma unroll
            for (int i = 0; i < 8; ++i)
                #pragma unroll
                for (int j = 0; j < 8; ++j)
                    acc[i][j] = fmaf(a[i], b[j], acc[i][j]);
        }
    }
    if (nchunk == 0) return;
    #pragma unroll
    for (int i = 0; i < 8; ++i) {
        int r = rowBase + ty * 8 + i;
        #pragma unroll
        for (int j = 0; j < 8; ++j)
            atomicAdd(&outp[r * H_DIM + colBase + tx * 8 + j], acc[i][j]);
    }
}

// ---------------- MFMA stage GEMM: one 16x16 tile per 1-wave block -----------
// out[256 x N] = act(A[256 x K] @ B[K x N] + bias); operands fp32 from global
// (L2-resident), converted fp32->bf16 in-register. Grid = 16*(N/16) blocks of
// 64 threads (1 wave) -> spreads across all 256 CUs.
// MODE 0: store; MODE 1: store + dementia dot; MODE 2: u-fuse only, no store.
template<int K, int N, int MODE>
__global__ __launch_bounds__(64)
void k_mstage(const float* __restrict__ A, const float* __restrict__ B,
              const float* __restrict__ bias, float* __restrict__ out, int act,
              const float* __restrict__ Wd, float* __restrict__ dem,
              const float* __restrict__ uW, float* __restrict__ u) {
    const int lane = threadIdx.x;
    const int wv = blockIdx.x;
    const int nct = N >> 4;
    const int r0 = (wv / nct) << 4;
    const int c0 = (wv % nct) << 4;
    const int lm   = lane & 15;
    const int lq   = (lane >> 4) << 3;   // k slice offset 0,8,16,24

    floatx4 accE = {0.f, 0.f, 0.f, 0.f};
    floatx4 accO = {0.f, 0.f, 0.f, 0.f};
    const float* ap = A + (size_t)(r0 + lm) * K + lq;
    const float* bp = B + (size_t)lq * N + c0 + lm;

    #pragma unroll 2
    for (int kb = 0; kb < K; kb += 64) {
        {   // k-step kb (even accumulator)
            float4 a0 = *(const float4*)(ap + kb);
            float4 a1 = *(const float4*)(ap + kb + 4);
            const float* bq = bp + (size_t)kb * N;
            float b0 = bq[0],           b1 = bq[(size_t)N];
            float b2 = bq[(size_t)2*N], b3 = bq[(size_t)3*N];
            float b4 = bq[(size_t)4*N], b5 = bq[(size_t)5*N];
            float b6 = bq[(size_t)6*N], b7 = bq[(size_t)7*N];
            short8 af, bf;
            af[0] = (short)f2b(a0.x); af[1] = (short)f2b(a0.y);
            af[2] = (short)f2b(a0.z); af[3] = (short)f2b(a0.w);
            af[4] = (short)f2b(a1.x); af[5] = (short)f2b(a1.y);
            af[6] = (short)f2b(a1.z); af[7] = (short)f2b(a1.w);
            bf[0] = (short)f2b(b0); bf[1] = (short)f2b(b1);
            bf[2] = (short)f2b(b2); bf[3] = (short)f2b(b3);
            bf[4] = (short)f2b(b4); bf[5] = (short)f2b(b5);
            bf[6] = (short)f2b(b6); bf[7] = (short)f2b(b7);
            accE = __builtin_amdgcn_mfma_f32_16x16x32_bf16(af, bf, accE, 0, 0, 0);
        }
        {   // k-step kb+32 (odd accumulator)
            const int k2 = kb + 32;
            float4 a0 = *(const float4*)(ap + k2);
            float4 a1 = *(const float4*)(ap + k2 + 4);
            const float* bq = bp + (size_t)k2 * N;
            float b0 = bq[0],           b1 = bq[(size_t)N];
            float b2 = bq[(size_t)2*N], b3 = bq[(size_t)3*N];
            float b4 = bq[(size_t)4*N], b5 = bq[(size_t)5*N];
            float b6 = bq[(size_t)6*N], b7 = bq[(size_t)7*N];
            short8 af, bf;
            af[0] = (short)f2b(a0.x); af[1] = (short)f2b(a0.y);
            af[2] = (short)f2b(a0.z); af[3] = (short)f2b(a0.w);
            af[4] = (short)f2b(a1.x); af[5] = (short)f2b(a1.y);
            af[6] = (short)f2b(a1.z); af[7] = (short)f2b(a1.w);
            bf[0] = (short)f2b(b0); bf[1] = (short)f2b(b1);
            bf[2] = (short)f2b(b2); bf[3] = (short)f2b(b3);
            bf[4] = (short)f2b(b4); bf[5] = (short)f2b(b5);
            bf[6] = (short)f2b(b6); bf[7] = (short)f2b(b7);
            accO = __builtin_amdgcn_mfma_f32_16x16x32_bf16(af, bf, accO, 0, 0, 0);
        }
    }

    const float bb = bias ? bias[c0 + lm] : 0.f;
    const int rq = (lane >> 4) << 2;
    float v[4];
    #pragma unroll
    for (int i = 0; i < 4; ++i) {
        v[i] = accE[i] + accO[i] + bb;
        if (act) v[i] = fmaxf(v[i], 0.f);
    }

    if (MODE == 2) {
        const float uw = uW[c0 + lm];
        #pragma unroll
        for (int i = 0; i < 4; ++i) {
            float p = v[i] * uw;
            #pragma unroll
            for (int off = 8; off; off >>= 1) p += __shfl_down(p, off, 16);
            if (lm == 0) atomicAdd(&u[r0 + rq + i], p);
        }
        return;
    }
    #pragma unroll
    for (int i = 0; i < 4; ++i)
        out[(size_t)(r0 + rq + i) * N + c0 + lm] = v[i];
    if (MODE == 1) {
        float p = 0.f;
        #pragma unroll
        for (int i = 0; i < 4; ++i)
            p += v[i] * Wd[(r0 + rq + i) * 256 + c0 + lm];
        #pragma unroll
        for (int off = 32; off; off >>= 1) p += __shfl_down(p, off, 64);
        if (lane == 0) atomicAdd(dem, p);
    }
}

__device__ __forceinline__ float sigmoidf(float x) {
    return 1.0f / (1.0f + expf(-x));
}

// final: v = P@u per row -> region scores; block 0 emits dementia pred
__global__ __launch_bounds__(256)
void k_final(const float* __restrict__ P, const float* __restrict__ u,
             const float* __restrict__ dem,
             const float* __restrict__ bc2a, const float* __restrict__ Wc2b,
             const float* __restrict__ bc2b, const float* __restrict__ bd,
             float* __restrict__ out) {
    __shared__ float red[4];
    const int b = blockIdx.x, t = threadIdx.x;
    float pv = P[b * 256 + t] * u[t];
    #pragma unroll
    for (int off = 32; off; off >>= 1) pv += __shfl_down(pv, off, 64);
    if ((t & 63) == 0) red[t >> 6] = pv;
    __syncthreads();
    if (t == 0) {
        float v = red[0] + red[1] + red[2] + red[3];
        float h2 = fmaxf(v + bc2a[0], 0.f);
        out[1 + b] = sigmoidf(h2 * Wc2b[0] + bc2b[0]);
        if (b == 0) out[0] = sigmoidf(*dem + bd[0]);
    }
}

extern "C" void kernel_launch(void* const* d_in, const int* in_sizes, int n_in,
                              void* d_out, int out_size, void* d_ws, size_t ws_size,
                              hipStream_t stream) {
    const float* x    = (const float*)d_in[0];
    const int*   idx  = (const int*)d_in[1];
    const float* Ws1a = (const float*)d_in[3];
    const float* bs1a = (const float*)d_in[4];
    const float* Ws1b = (const float*)d_in[5];
    const float* bs1b = (const float*)d_in[6];
    const float* Ws2a = (const float*)d_in[7];
    const float* bs2a = (const float*)d_in[8];
    const float* Ws2b = (const float*)d_in[9];
    const float* bs2b = (const float*)d_in[10];
    const float* Wc1a = (const float*)d_in[11];
    const float* bc1a = (const float*)d_in[12];
    const float* Wc1b = (const float*)d_in[13];
    const float* bc1b = (const float*)d_in[14];
    const float* Wc2a = (const float*)d_in[15];
    const float* bc2a = (const float*)d_in[16];
    const float* Wc2b = (const float*)d_in[17];
    const float* bc2b = (const float*)d_in[18];
    const float* Wd   = (const float*)d_in[19];
    const float* bd   = (const float*)d_in[20];
    float* out = (float*)d_out;
    const int E = in_sizes[1] / 2;

    float* w    = (float*)d_ws;
    float* P    = w;                  // 65536
    float* Y1   = P + 65536;          // 131072
    float* bufA = Y1 + 131072;        // 131072
    float* bufB = bufA + 131072;      // 131072
    float* feat = bufB + 131072;      // 65536
    float* u    = feat + 65536;       // 256
    float* dem  = u + 256;            // 64 (dem + pad)
    float* WtF  = dem + 64;           // Wt bf16: 512*30016*2B
    const size_t WT_F = ((size_t)H_DIM * KP) / 2;     // 7,684,096 f32 slots
    float* XbF  = WtF + WT_F;         // xb bf16: 256*30016*2B
    const size_t XB_F = ((size_t)N_NODES * KP) / 2;   // 3,842,048 f32 slots
    float* Y1p  = XbF + XB_F;
    unsigned short* Wt = (unsigned short*)WtF;
    unsigned short* xb = (unsigned short*)XbF;

    // split-K slicing: 469 chunks of BK=64 (KP=30016)
    const long long fixed = (long long)(Y1p - w);
    const long long avail = (long long)(ws_size / 4) - fixed;
    int maxsplit = (avail > 0) ? (int)(avail / 131072) : 0;
    int nz = 0, kc = 0;
    const int CH64 = 469;
    if (maxsplit >= 2) {
        int splits = maxsplit < 64 ? maxsplit : 64;  // cps=8 -> nz=59, 472 blocks
        int cps = (CH64 + splits - 1) / splits;
        nz = (CH64 + cps - 1) / cps;
        kc = cps * 64;                // elements per z-slice
    }

    if (nz > 0) {
        // prepass: Wt, xb, P=I, zero u/dem (one dispatch)
        k_prep<<<7569, 256, 0, stream>>>(Ws1a, x, Wt, xb, P, dem, u);
        // Y1 = x @ Ws1a   (P@(x@W) == (P@x)@W)
        k_gemm_bf16<<<8 * nz, 256, 0, stream>>>(xb, Wt, Y1p, kc);
        // split-K reduce + edge atomics into P (one dispatch)
        k_reduce<<<128 + (E + 255) / 256, 256, 0, stream>>>(
            (const float4*)Y1p, (float4*)Y1, nz, idx, E, P);
    } else {
        k_init_P<<<256, 256, 0, stream>>>(P, dem, u);
        k_count_edges<<<(E + 255) / 256, 256, 0, stream>>>(idx, E, P);
        k_zero<<<512, 256, 0, stream>>>(Y1, N_NODES * H_DIM);
        k_gemm_big_atomic<<<dim3(4, 2, 63), 256, 0, stream>>>(x, Ws1a, Y1, 480);
    }

    // stage chain (stream order is the barrier); 16x16 tile per 1-wave block
    k_mstage<256, 512, 0><<<512, 64, 0, stream>>>(P,    Y1,   bs1a, bufA, 1, 0, 0, 0, 0);
    k_mstage<512, 512, 0><<<512, 64, 0, stream>>>(bufA, Ws1b, bs1b, bufB, 1, 0, 0, 0, 0);
    k_mstage<256, 512, 0><<<512, 64, 0, stream>>>(P,    bufB, 0,    bufA, 0, 0, 0, 0, 0);
    k_mstage<512, 256, 0><<<256, 64, 0, stream>>>(bufA, Ws2a, bs2a, bufB, 1, 0, 0, 0, 0);
    k_mstage<256, 256, 1><<<256, 64, 0, stream>>>(bufB, Ws2b, bs2b, feat, 0, Wd, dem, 0, 0);
    k_mstage<256, 256, 0><<<256, 64, 0, stream>>>(P,    feat, 0,    bufA, 0, 0, 0, 0, 0);
    k_mstage<256, 512, 0><<<512, 64, 0, stream>>>(bufA, Wc1a, bc1a, bufB, 1, 0, 0, 0, 0);
    k_mstage<512, 512, 2><<<512, 64, 0, stream>>>(bufB, Wc1b, bc1b, 0,    1, 0, 0, Wc2a, u);
    k_final<<<256, 256, 0, stream>>>(P, u, dem, bc2a, Wc2b, bc2b, bd, out);
}